// Round 5
// baseline (59.450 us; speedup 1.0000x reference)
//
#include <hip/hip_runtime.h>

#define BB 8
#define GG 8
#define HH 4
#define KK 8192
#define DD 128
#define RR 32
#define THREADS 256
#define KPB 512                     // keys per block
#define KPW (KPB / 4)               // keys per wave = 128
#define NB  (KPW / 8)               // batches per wave = 16 (8 keys each)

typedef float f4 __attribute__((ext_vector_type(4)));

#define DOT4(v, u) ((v).x * (u).x + (v).y * (u).y + (v).z * (u).z + (v).w * (u).w)

__global__ __launch_bounds__(THREADS, 4) void lowrank_scores(
    const float* __restrict__ query,
    const float* __restrict__ key,
    const float* __restrict__ weight,
    float* __restrict__ out)
{
    __shared__ float w_lds[DD * RR];   // 16 KB, layout [d][r]
    __shared__ float qproj[HH][RR];
    __shared__ float u_lds[HH][DD];

    const int bpbg = KK / KPB;         // 16 blocks per (b,g)
    const int bg   = blockIdx.x / bpbg;
    const int kblk = blockIdx.x % bpbg;
    const int g    = bg & (GG - 1);
    const int tid  = threadIdx.x;
    const int lane = tid & 63;
    const int wave = tid >> 6;
    const int l7   = lane & 7;         // position within 8-lane key-group
    const int kg   = lane >> 3;        // which of 8 concurrent keys

    // lane's base: key row (.. + kg), float offset l7*4; chunk j adds 32j floats
    const float* keyb = key + ((size_t)bg * KK + (size_t)kblk * KPB
                               + (size_t)wave * KPW + kg) * DD + l7 * 4;

    f4 kr[2][4];
    // nontemporal: keys are read exactly once — keep L2 clean
    #define LOADB(s, bt)                                                      \
        {                                                                     \
            const f4* p = (const f4*)(keyb + (size_t)(bt) * (8 * DD));        \
            kr[s][0] = __builtin_nontemporal_load(p);                         \
            kr[s][1] = __builtin_nontemporal_load(p + 8);                     \
            kr[s][2] = __builtin_nontemporal_load(p + 16);                    \
            kr[s][3] = __builtin_nontemporal_load(p + 24);                    \
        }

    // ---- prefetch first two key batches BEFORE the prologue: HBM streaming
    //      starts at cycle 0, prologue compute hides under load latency ----
    LOADB(0, 0);
    LOADB(1, 1);

    // ---- prologue: u[h] = W (W^T q[h]) ----
    {
        const float4* wg = (const float4*)(weight + (size_t)g * DD * RR);
        float4* wl = (float4*)w_lds;
        for (int i = tid; i < DD * RR / 4; i += THREADS) wl[i] = wg[i];
    }
    __syncthreads();

    if (tid < HH * RR) {
        const int h = tid >> 5, r = tid & (RR - 1);
        const float* qp = query + ((size_t)bg * HH + h) * DD;
        float s = 0.f;
        #pragma unroll 8
        for (int d = 0; d < DD; ++d) s += qp[d] * w_lds[d * RR + r];
        qproj[h][r] = s;
    }
    __syncthreads();

    for (int idx = tid; idx < HH * DD; idx += THREADS) {
        const int h = idx >> 7, d = idx & (DD - 1);
        float s = 0.f;
        #pragma unroll
        for (int rr = 0; rr < RR; ++rr) {
            const int r = (rr + d) & (RR - 1);   // rotated: bank-conflict-free
            s += qproj[h][r] * w_lds[d * RR + r];
        }
        u_lds[h][d] = s;
    }
    __syncthreads();

    f4 uf[HH][4];                      // 64 VGPR: u fragments
    #pragma unroll
    for (int h = 0; h < HH; ++h)
        #pragma unroll
        for (int j = 0; j < 4; ++j)
            uf[h][j] = *(const f4*)&u_lds[h][(l7 + 8 * j) * 4];

    float* outb = out + (size_t)bg * HH * KK + (size_t)kblk * KPB + wave * KPW;
    const float scale = 0.08838834764831845f;   // 128^-0.5

    #define COMPUTEB(s, bt)                                                   \
        {                                                                     \
            float a0 = DOT4(kr[s][0], uf[0][0]) + DOT4(kr[s][1], uf[0][1])    \
                     + DOT4(kr[s][2], uf[0][2]) + DOT4(kr[s][3], uf[0][3]);   \
            float a1 = DOT4(kr[s][0], uf[1][0]) + DOT4(kr[s][1], uf[1][1])    \
                     + DOT4(kr[s][2], uf[1][2]) + DOT4(kr[s][3], uf[1][3]);   \
            float a2 = DOT4(kr[s][0], uf[2][0]) + DOT4(kr[s][1], uf[2][1])    \
                     + DOT4(kr[s][2], uf[2][2]) + DOT4(kr[s][3], uf[2][3]);   \
            float a3 = DOT4(kr[s][0], uf[3][0]) + DOT4(kr[s][1], uf[3][1])    \
                     + DOT4(kr[s][2], uf[3][2]) + DOT4(kr[s][3], uf[3][3]);   \
            a0 += __shfl_xor(a0, 1); a1 += __shfl_xor(a1, 1);                 \
            a2 += __shfl_xor(a2, 1); a3 += __shfl_xor(a3, 1);                 \
            a0 += __shfl_xor(a0, 2); a1 += __shfl_xor(a1, 2);                 \
            a2 += __shfl_xor(a2, 2); a3 += __shfl_xor(a3, 2);                 \
            a0 += __shfl_xor(a0, 4); a1 += __shfl_xor(a1, 4);                 \
            a2 += __shfl_xor(a2, 4); a3 += __shfl_xor(a3, 4);                 \
            if (l7 == 0) {                                                    \
                const int kw = (bt) * 8 + kg;                                 \
                outb[(size_t)0 * KK + kw] = a0 * scale;                       \
                outb[(size_t)1 * KK + kw] = a1 * scale;                       \
                outb[(size_t)2 * KK + kw] = a2 * scale;                       \
                outb[(size_t)3 * KK + kw] = a3 * scale;                       \
            }                                                                 \
        }

    // compute-then-load: compute(bt) waits on a load issued 2 iters earlier
    #pragma unroll
    for (int bt = 0; bt < NB; ++bt) {
        COMPUTEB(bt & 1, bt);
        if (bt + 2 < NB) LOADB(bt & 1, bt + 2);
    }
    #undef LOADB
    #undef COMPUTEB
}

extern "C" void kernel_launch(void* const* d_in, const int* in_sizes, int n_in,
                              void* d_out, int out_size, void* d_ws, size_t ws_size,
                              hipStream_t stream) {
    const float* query  = (const float*)d_in[0];
    const float* key    = (const float*)d_in[1];
    const float* weight = (const float*)d_in[2];
    float* out = (float*)d_out;

    const int grid = BB * GG * (KK / KPB);   // 1024 blocks = 4 per CU (one round)
    lowrank_scores<<<dim3(grid), dim3(THREADS), 0, stream>>>(query, key, weight, out);
}

// Round 6
// 54.134 us; speedup vs baseline: 1.0982x; 1.0982x over previous
//
#include <hip/hip_runtime.h>

#define BB 8
#define GG 8
#define HH 4
#define KK 8192
#define DD 128
#define RR 32
#define THREADS 256
#define KPB 512                     // keys per block
#define KPW (KPB / 4)               // keys per wave = 128
#define NB  (KPW / 8)               // batches per wave = 16 (8 keys each)

#define DOT4(v, u) ((v).x * (u).x + (v).y * (u).y + (v).z * (u).z + (v).w * (u).w)

__global__ __launch_bounds__(THREADS, 4) void lowrank_scores(
    const float* __restrict__ query,
    const float* __restrict__ key,
    const float* __restrict__ weight,
    float* __restrict__ out)
{
    __shared__ float w_lds[DD * RR];   // 16 KB, layout [d][r]
    __shared__ float q_lds[HH * DD];   // 2 KB
    __shared__ float qproj[HH][RR];
    __shared__ float u_lds[HH][DD];

    const int bpbg = KK / KPB;         // 16 blocks per (b,g)
    const int bg   = blockIdx.x / bpbg;
    const int kblk = blockIdx.x % bpbg;
    const int g    = bg & (GG - 1);
    const int tid  = threadIdx.x;

    // ---- stage W[g] (16 KB) and this bg's 4 q rows (2 KB) into LDS ----
    {
        const float4* wg = (const float4*)(weight + (size_t)g * DD * RR);
        float4* wl = (float4*)w_lds;
        for (int i = tid; i < DD * RR / 4; i += THREADS) wl[i] = wg[i];
        if (tid < HH * DD / 4)
            ((float4*)q_lds)[tid] =
                ((const float4*)(query + (size_t)bg * HH * DD))[tid];
    }
    __syncthreads();

    // ---- qproj[h][r]: all 256 threads — 2 threads per (h,r), 64 d's each,
    //      combined with one adjacent-lane shuffle. LDS reads are broadcast
    //      or 2-way (free). ----
    {
        const int p = tid >> 1, half = tid & 1;
        const int h = p >> 5, r = p & (RR - 1);
        const int dbase = half * 64;
        float s = 0.f;
        #pragma unroll 16
        for (int d0 = 0; d0 < 64; ++d0) {
            const int d = dbase + d0;
            s += q_lds[h * DD + d] * w_lds[d * RR + r];
        }
        s += __shfl_xor(s, 1);
        if (half == 0) qproj[h][r] = s;
    }
    __syncthreads();

    // ---- u[h][d] = sum_r qproj[h][r] * w[d][r] (rotated r: conflict-free) ----
    for (int idx = tid; idx < HH * DD; idx += THREADS) {
        const int h = idx >> 7, d = idx & (DD - 1);
        float s = 0.f;
        #pragma unroll
        for (int rr = 0; rr < RR; ++rr) {
            const int r = (rr + d) & (RR - 1);
            s += qproj[h][r] * w_lds[d * RR + r];
        }
        u_lds[h][d] = s;
    }
    __syncthreads();

    // ---- main loop: 8 lanes per key, lane owns chunks {(l&7)+8j, j=0..3} ----
    const int lane = tid & 63;
    const int wave = tid >> 6;
    const int l7   = lane & 7;         // position within 8-lane key-group
    const int kg   = lane >> 3;        // which of 8 concurrent keys

    float4 uf[HH][4];                  // 64 VGPR: u fragments
    #pragma unroll
    for (int h = 0; h < HH; ++h)
        #pragma unroll
        for (int j = 0; j < 4; ++j)
            uf[h][j] = *(const float4*)&u_lds[h][(l7 + 8 * j) * 4];

    const float* keyb = key + ((size_t)bg * KK + (size_t)kblk * KPB
                               + (size_t)wave * KPW + kg) * DD + l7 * 4;
    float* outb = out + (size_t)bg * HH * KK + (size_t)kblk * KPB + wave * KPW;
    const float scale = 0.08838834764831845f;   // 128^-0.5

    float4 kr[2][4];

    #define LOADB(s, bt)                                                      \
        {                                                                     \
            const float* p = keyb + (size_t)(bt) * (8 * DD);                  \
            kr[s][0] = *(const float4*)(p);                                   \
            kr[s][1] = *(const float4*)(p + 32);                              \
            kr[s][2] = *(const float4*)(p + 64);                              \
            kr[s][3] = *(const float4*)(p + 96);                              \
        }

    #define COMPUTEB(s, bt)                                                   \
        {                                                                     \
            float a0 = DOT4(kr[s][0], uf[0][0]) + DOT4(kr[s][1], uf[0][1])    \
                     + DOT4(kr[s][2], uf[0][2]) + DOT4(kr[s][3], uf[0][3]);   \
            float a1 = DOT4(kr[s][0], uf[1][0]) + DOT4(kr[s][1], uf[1][1])    \
                     + DOT4(kr[s][2], uf[1][2]) + DOT4(kr[s][3], uf[1][3]);   \
            float a2 = DOT4(kr[s][0], uf[2][0]) + DOT4(kr[s][1], uf[2][1])    \
                     + DOT4(kr[s][2], uf[2][2]) + DOT4(kr[s][3], uf[2][3]);   \
            float a3 = DOT4(kr[s][0], uf[3][0]) + DOT4(kr[s][1], uf[3][1])    \
                     + DOT4(kr[s][2], uf[3][2]) + DOT4(kr[s][3], uf[3][3]);   \
            a0 += __shfl_xor(a0, 1); a1 += __shfl_xor(a1, 1);                 \
            a2 += __shfl_xor(a2, 1); a3 += __shfl_xor(a3, 1);                 \
            a0 += __shfl_xor(a0, 2); a1 += __shfl_xor(a1, 2);                 \
            a2 += __shfl_xor(a2, 2); a3 += __shfl_xor(a3, 2);                 \
            a0 += __shfl_xor(a0, 4); a1 += __shfl_xor(a1, 4);                 \
            a2 += __shfl_xor(a2, 4); a3 += __shfl_xor(a3, 4);                 \
            if (l7 == 0) {                                                    \
                const int kw = (bt) * 8 + kg;                                 \
                outb[(size_t)0 * KK + kw] = a0 * scale;                       \
                outb[(size_t)1 * KK + kw] = a1 * scale;                       \
                outb[(size_t)2 * KK + kw] = a2 * scale;                       \
                outb[(size_t)3 * KK + kw] = a3 * scale;                       \
            }                                                                 \
        }

    LOADB(0, 0);
    #pragma unroll
    for (int bt = 0; bt < NB; ++bt) {
        if (bt + 1 < NB) LOADB((bt + 1) & 1, bt + 1);
        COMPUTEB(bt & 1, bt);
    }
    #undef LOADB
    #undef COMPUTEB
}

extern "C" void kernel_launch(void* const* d_in, const int* in_sizes, int n_in,
                              void* d_out, int out_size, void* d_ws, size_t ws_size,
                              hipStream_t stream) {
    const float* query  = (const float*)d_in[0];
    const float* key    = (const float*)d_in[1];
    const float* weight = (const float*)d_in[2];
    float* out = (float*)d_out;

    const int grid = BB * GG * (KK / KPB);   // 1024 blocks = 4 per CU (one round)
    lowrank_scores<<<dim3(grid), dim3(THREADS), 0, stream>>>(query, key, weight, out);
}

// Round 7
// 53.207 us; speedup vs baseline: 1.1173x; 1.0174x over previous
//
#include <hip/hip_runtime.h>

#define BB 8
#define GG 8
#define HH 4
#define KK 8192
#define DD 128
#define RR 32
#define THREADS 512
#define WPB (THREADS / 64)          // 8 waves per block
#define KPB 1024                    // keys per block
#define KPW (KPB / WPB)             // keys per wave = 128
#define NB  (KPW / 8)               // batches per wave = 16 (8 keys each)

#define DOT4(v, u) ((v).x * (u).x + (v).y * (u).y + (v).z * (u).z + (v).w * (u).w)

__global__ __launch_bounds__(THREADS, 4) void lowrank_scores(
    const float* __restrict__ query,
    const float* __restrict__ key,
    const float* __restrict__ weight,
    float* __restrict__ out)
{
    __shared__ float w_lds[DD * RR];   // 16 KB, layout [d][r]
    __shared__ float q_lds[HH * DD];   // 2 KB
    __shared__ float qproj[HH][RR];
    __shared__ float u_lds[HH][DD];

    const int bpbg = KK / KPB;         // 8 blocks per (b,g)
    const int bg   = blockIdx.x / bpbg;
    const int kblk = blockIdx.x % bpbg;
    const int g    = bg & (GG - 1);
    const int tid  = threadIdx.x;

    // ---- stage W[g] (16 KB) and this bg's 4 q rows (2 KB) into LDS ----
    {
        const float4* wg = (const float4*)(weight + (size_t)g * DD * RR);
        float4* wl = (float4*)w_lds;
        #pragma unroll
        for (int i = tid; i < DD * RR / 4; i += THREADS) wl[i] = wg[i];
        if (tid < HH * DD / 4)
            ((float4*)q_lds)[tid] =
                ((const float4*)(query + (size_t)bg * HH * DD))[tid];
    }
    __syncthreads();

    // ---- qproj[h][r]: 4 threads per (h,r), 32 d's each, 2-step shfl combine ----
    {
        const int p = tid >> 2, quad = tid & 3;
        const int h = p >> 5, r = p & (RR - 1);
        const int dbase = quad * 32;
        float s = 0.f;
        #pragma unroll 8
        for (int d0 = 0; d0 < 32; ++d0) {
            const int d = dbase + d0;
            s += q_lds[h * DD + d] * w_lds[d * RR + r];
        }
        s += __shfl_xor(s, 1);
        s += __shfl_xor(s, 2);
        if (quad == 0) qproj[h][r] = s;
    }
    __syncthreads();

    // ---- u[h][d] = sum_r qproj[h][r] * w[d][r] — one item per thread ----
    {
        const int h = tid >> 7, d = tid & (DD - 1);
        float s = 0.f;
        #pragma unroll
        for (int rr = 0; rr < RR; ++rr) {
            const int r = (rr + d) & (RR - 1);   // rotated: conflict-free
            s += qproj[h][r] * w_lds[d * RR + r];
        }
        u_lds[h][d] = s;
    }
    __syncthreads();

    // ---- main loop: 8 lanes per key, lane owns chunks {(l&7)+8j, j=0..3} ----
    const int lane = tid & 63;
    const int wave = tid >> 6;
    const int l7   = lane & 7;         // position within 8-lane key-group
    const int kg   = lane >> 3;        // which of 8 concurrent keys

    float4 uf[HH][4];                  // 64 VGPR: u fragments
    #pragma unroll
    for (int h = 0; h < HH; ++h)
        #pragma unroll
        for (int j = 0; j < 4; ++j)
            uf[h][j] = *(const float4*)&u_lds[h][(l7 + 8 * j) * 4];

    const float* keyb = key + ((size_t)bg * KK + (size_t)kblk * KPB
                               + (size_t)wave * KPW + kg) * DD + l7 * 4;
    float* outb = out + (size_t)bg * HH * KK + (size_t)kblk * KPB + wave * KPW;
    const float scale = 0.08838834764831845f;   // 128^-0.5

    float4 kr[2][4];

    #define LOADB(s, bt)                                                      \
        {                                                                     \
            const float* p = keyb + (size_t)(bt) * (8 * DD);                  \
            kr[s][0] = *(const float4*)(p);                                   \
            kr[s][1] = *(const float4*)(p + 32);                              \
            kr[s][2] = *(const float4*)(p + 64);                              \
            kr[s][3] = *(const float4*)(p + 96);                              \
        }

    #define COMPUTEB(s, bt)                                                   \
        {                                                                     \
            float a0 = DOT4(kr[s][0], uf[0][0]) + DOT4(kr[s][1], uf[0][1])    \
                     + DOT4(kr[s][2], uf[0][2]) + DOT4(kr[s][3], uf[0][3]);   \
            float a1 = DOT4(kr[s][0], uf[1][0]) + DOT4(kr[s][1], uf[1][1])    \
                     + DOT4(kr[s][2], uf[1][2]) + DOT4(kr[s][3], uf[1][3]);   \
            float a2 = DOT4(kr[s][0], uf[2][0]) + DOT4(kr[s][1], uf[2][1])    \
                     + DOT4(kr[s][2], uf[2][2]) + DOT4(kr[s][3], uf[2][3]);   \
            float a3 = DOT4(kr[s][0], uf[3][0]) + DOT4(kr[s][1], uf[3][1])    \
                     + DOT4(kr[s][2], uf[3][2]) + DOT4(kr[s][3], uf[3][3]);   \
            a0 += __shfl_xor(a0, 1); a1 += __shfl_xor(a1, 1);                 \
            a2 += __shfl_xor(a2, 1); a3 += __shfl_xor(a3, 1);                 \
            a0 += __shfl_xor(a0, 2); a1 += __shfl_xor(a1, 2);                 \
            a2 += __shfl_xor(a2, 2); a3 += __shfl_xor(a3, 2);                 \
            a0 += __shfl_xor(a0, 4); a1 += __shfl_xor(a1, 4);                 \
            a2 += __shfl_xor(a2, 4); a3 += __shfl_xor(a3, 4);                 \
            if (l7 == 0) {                                                    \
                const int kw = (bt) * 8 + kg;                                 \
                outb[(size_t)0 * KK + kw] = a0 * scale;                       \
                outb[(size_t)1 * KK + kw] = a1 * scale;                       \
                outb[(size_t)2 * KK + kw] = a2 * scale;                       \
                outb[(size_t)3 * KK + kw] = a3 * scale;                       \
            }                                                                 \
        }

    LOADB(0, 0);
    #pragma unroll
    for (int bt = 0; bt < NB; ++bt) {
        if (bt + 1 < NB) LOADB((bt + 1) & 1, bt + 1);
        COMPUTEB(bt & 1, bt);
    }
    #undef LOADB
    #undef COMPUTEB
}

extern "C" void kernel_launch(void* const* d_in, const int* in_sizes, int n_in,
                              void* d_out, int out_size, void* d_ws, size_t ws_size,
                              hipStream_t stream) {
    const float* query  = (const float*)d_in[0];
    const float* key    = (const float*)d_in[1];
    const float* weight = (const float*)d_in[2];
    float* out = (float*)d_out;

    const int grid = BB * GG * (KK / KPB);   // 512 blocks = 2 per CU (one round)
    lowrank_scores<<<dim3(grid), dim3(THREADS), 0, stream>>>(query, key, weight, out);
}